// Round 1
// baseline (169.760 us; speedup 1.0000x reference)
//
#include <hip/hip_runtime.h>
#include <hip/hip_bf16.h>

// out[b,p,:] = sequence[b, positions[b,p], :]
// B=8, S=4096, H=1024, P=512 (from setup_inputs).
// One block per (b,p) output row; 256 threads x float4 = 1024 floats = one row.
__global__ void __launch_bounds__(256)
onehot_gather_kernel(const float* __restrict__ seq,
                     const int* __restrict__ pos,
                     float* __restrict__ out,
                     int S, int H, int P) {
    const int p = blockIdx.x;          // position index within batch
    const int b = blockIdx.y;          // batch index
    const int row = b * P + p;         // flat output row

    // Wave-uniform position read (compiler emits scalar load).
    const int s = pos[row];

    const float4* __restrict__ src =
        reinterpret_cast<const float4*>(seq + ((size_t)b * S + (size_t)s) * H);
    float4* __restrict__ dst =
        reinterpret_cast<float4*>(out + (size_t)row * H);

    const int n4 = H >> 2;             // 256 float4 per row
    for (int i = threadIdx.x; i < n4; i += blockDim.x) {
        dst[i] = src[i];
    }
}

extern "C" void kernel_launch(void* const* d_in, const int* in_sizes, int n_in,
                              void* d_out, int out_size, void* d_ws, size_t ws_size,
                              hipStream_t stream) {
    const float* seq = (const float*)d_in[0];   // [B, S, H] fp32
    const int*   pos = (const int*)d_in[1];     // [B, P] int32 (jax demotes int64)
    float*       out = (float*)d_out;           // [B, P, H] fp32

    const int B = 8, S = 4096, H = 1024, P = 512;
    // sanity: in_sizes[0] == B*S*H, in_sizes[1] == B*P, out_size == B*P*H

    dim3 grid(P, B);
    dim3 block(256);
    onehot_gather_kernel<<<grid, block, 0, stream>>>(seq, pos, out, S, H, P);
}

// Round 2
// 168.485 us; speedup vs baseline: 1.0076x; 1.0076x over previous
//
#include <hip/hip_runtime.h>
#include <hip/hip_bf16.h>

// out[b,p,:] = sequence[b, positions[b,p], :]
// B=8, S=4096, H=1024, P=512. Pure row gather: 16 MiB read + 16 MiB write.
// 4 rows per block, 256 threads; thread i copies float4 #i of each row
// (H/4 = 256 float4 per row). 4 independent loads in flight per thread.
__global__ void __launch_bounds__(256)
onehot_gather_kernel(const float* __restrict__ seq,
                     const int* __restrict__ pos,
                     float* __restrict__ out) {
    constexpr int S = 4096, H = 1024, P = 512;
    constexpr int RPB = 4;                       // rows per block
    const int row0 = blockIdx.x * RPB;
    const int i = threadIdx.x;                   // float4 index within row

    int s[RPB];
#pragma unroll
    for (int r = 0; r < RPB; ++r) s[r] = pos[row0 + r];

    float4 v[RPB];
#pragma unroll
    for (int r = 0; r < RPB; ++r) {
        const int row = row0 + r;
        const int b = row / P;
        const float4* __restrict__ src =
            reinterpret_cast<const float4*>(seq + ((size_t)b * S + (size_t)s[r]) * H);
        v[r] = src[i];
    }
#pragma unroll
    for (int r = 0; r < RPB; ++r) {
        float4* __restrict__ dst =
            reinterpret_cast<float4*>(out + (size_t)(row0 + r) * H);
        dst[i] = v[r];
    }
}

extern "C" void kernel_launch(void* const* d_in, const int* in_sizes, int n_in,
                              void* d_out, int out_size, void* d_ws, size_t ws_size,
                              hipStream_t stream) {
    const float* seq = (const float*)d_in[0];   // [B, S, H] fp32
    const int*   pos = (const int*)d_in[1];     // [B, P] int32
    float*       out = (float*)d_out;           // [B, P, H] fp32

    constexpr int B = 8, P = 512, RPB = 4;
    dim3 grid((B * P) / RPB);                    // 1024 blocks
    dim3 block(256);
    onehot_gather_kernel<<<grid, block, 0, stream>>>(seq, pos, out);
}